// Round 1
// baseline (144.016 us; speedup 1.0000x reference)
//
#include <hip/hip_runtime.h>
#include <hip/hip_bf16.h>
#include <stdint.h>

#define T_DIM 1024
#define B_DIM 8

typedef __attribute__((ext_vector_type(8))) short short8;
typedef __attribute__((ext_vector_type(4))) float f32x4;

__device__ inline void gll16(const void* g, void* l) {
  __builtin_amdgcn_global_load_lds((__attribute__((address_space(1))) void*)g,
                                   (__attribute__((address_space(3))) void*)l,
                                   16, 0, 0);
}

// ---------------- fp32 -> bf16 convert ----------------
__global__ __launch_bounds__(256) void convert_kernel(const float* __restrict__ F,
                                                      __hip_bfloat16* __restrict__ Fb) {
  const int t = blockIdx.x * 256 + threadIdx.x;   // 8192 blocks * 256 = 2M threads * 4 elems
  const float4 v = ((const float4*)F)[t];
  union { __hip_bfloat16 h[4]; uint64_t u; } p;
  p.h[0] = __float2bfloat16(v.x);
  p.h[1] = __float2bfloat16(v.y);
  p.h[2] = __float2bfloat16(v.z);
  p.h[3] = __float2bfloat16(v.w);
  ((uint64_t*)Fb)[t] = p.u;
}

// ---------------- Gram GEMM: S = (F F^T) * 10 ----------------
// 128x128 tile per block (256 threads = 4 waves, each wave 64x64),
// BK=32 (one 16x16x32 MFMA per K-chunk), global_load_lds width-16 staging.
__global__ __launch_bounds__(256) void gram_kernel(const __hip_bfloat16* __restrict__ Fb,
                                                   float* __restrict__ S) {
  __shared__ __hip_bfloat16 As[128 * 32];
  __shared__ __hip_bfloat16 Bs[128 * 32];
  const int b = blockIdx.z;
  const __hip_bfloat16* F = Fb + ((size_t)b << 20);
  float* Sb = S + ((size_t)b << 20);
  const int tid  = threadIdx.x;
  const int lane = tid & 63;
  const int wave = tid >> 6;
  const int wrow = (wave >> 1) * 64;
  const int wcol = (wave & 1) * 64;
  const int row0 = blockIdx.y * 128;
  const int col0 = blockIdx.x * 128;

  // staging: thread t loads 8 bf16 (16B) from row (t>>2), k-offset (t&3)*8
  const int sr = tid >> 2;
  const int sk = (tid & 3) * 8;

  f32x4 acc[4][4];
#pragma unroll
  for (int i = 0; i < 4; i++)
#pragma unroll
    for (int j = 0; j < 4; j++) acc[i][j] = (f32x4){0.f, 0.f, 0.f, 0.f};

  const int fr = lane & 15;         // fragment row/col within 16
  const int fk = (lane >> 4) * 8;   // fragment k offset

  for (int k0 = 0; k0 < T_DIM; k0 += 32) {
    __syncthreads();  // protect LDS from previous iter's readers
    gll16(F + (size_t)(row0 + sr) * T_DIM + k0 + sk,      As + tid * 8);
    gll16(F + (size_t)(row0 + sr + 64) * T_DIM + k0 + sk, As + 64 * 32 + tid * 8);
    gll16(F + (size_t)(col0 + sr) * T_DIM + k0 + sk,      Bs + tid * 8);
    gll16(F + (size_t)(col0 + sr + 64) * T_DIM + k0 + sk, Bs + 64 * 32 + tid * 8);
    __syncthreads();  // drains vmcnt -> LDS populated

    short8 af[4], bf[4];
#pragma unroll
    for (int t = 0; t < 4; t++) {
      af[t] = *(const short8*)(As + (wrow + t * 16 + fr) * 32 + fk);
      bf[t] = *(const short8*)(Bs + (wcol + t * 16 + fr) * 32 + fk);
    }
#pragma unroll
    for (int ti = 0; ti < 4; ti++)
#pragma unroll
      for (int tj = 0; tj < 4; tj++)
        acc[ti][tj] = __builtin_amdgcn_mfma_f32_16x16x32_bf16(af[ti], bf[tj], acc[ti][tj], 0, 0, 0);
  }

  // epilogue: C/D layout col=lane&15, row=(lane>>4)*4+r  [m89-verified]
#pragma unroll
  for (int ti = 0; ti < 4; ti++)
#pragma unroll
    for (int tj = 0; tj < 4; tj++)
#pragma unroll
      for (int r = 0; r < 4; r++) {
        const int row = row0 + wrow + ti * 16 + (lane >> 4) * 4 + r;
        const int col = col0 + wcol + tj * 16 + (lane & 15);
        Sb[(size_t)row * T_DIM + col] = acc[ti][tj][r] * 10.0f;
      }
}

// ---------------- per-row pass ----------------
// one block (256 thr) per (b,i) row: max_{j<L} S, then den/cnt/A sums + validity
__global__ __launch_bounds__(256) void row_kernel(const float* __restrict__ S,
                                                  const float* __restrict__ M,
                                                  const int* __restrict__ icl,
                                                  float* __restrict__ row_val,
                                                  int* __restrict__ row_bad) {
  const int row = blockIdx.x;           // 0..8191
  const int b = row >> 10;
  const int i = row & 1023;
  const int L = icl[b] + 1;
  if (i >= L) {                         // block-uniform early out
    if (threadIdx.x == 0) { row_val[row] = 0.0f; row_bad[row] = 0; }
    return;
  }
  const int tid  = threadIdx.x;
  const int lane = tid & 63;
  const int wave = tid >> 6;
  const float4 s4 = ((const float4*)(S + (size_t)row * T_DIM))[tid];
  const float4 m4 = ((const float4*)(M + (size_t)row * T_DIM))[tid];
  const float sv[4] = {s4.x, s4.y, s4.z, s4.w};
  const float mv[4] = {m4.x, m4.y, m4.z, m4.w};
  const int j0 = tid * 4;

  float mx = -1e30f;
#pragma unroll
  for (int c = 0; c < 4; c++)
    if (j0 + c < L) mx = fmaxf(mx, sv[c]);
  for (int o = 32; o > 0; o >>= 1) mx = fmaxf(mx, __shfl_down(mx, o, 64));
  __shared__ float wred[4];
  if (lane == 0) wred[wave] = mx;
  __syncthreads();
  mx = fmaxf(fmaxf(wred[0], wred[1]), fmaxf(wred[2], wred[3]));

  float den = 0.f, cnt = 0.f, asum = 0.f;
  bool bad = false;
#pragma unroll
  for (int c = 0; c < 4; c++) {
    const int j = j0 + c;
    if (j < L) {
      const float d = sv[c] - mx;
      const float mm = mv[c];
      if (j != i) {
        den += __expf(d);
        cnt += mm;
        asum += mm * d;
      }
      const float sane = (j == i && i != 0) ? 1.0f : 0.0f;
      bad = bad || (mm != sane);
    }
  }
  for (int o = 32; o > 0; o >>= 1) {
    den  += __shfl_down(den, o, 64);
    cnt  += __shfl_down(cnt, o, 64);
    asum += __shfl_down(asum, o, 64);
  }
  const bool wbad = (__ballot(bad) != 0ull);
  __shared__ float dred[4], cred[4], ared[4];
  __shared__ int bred[4];
  if (lane == 0) { dred[wave] = den; cred[wave] = cnt; ared[wave] = asum; bred[wave] = wbad ? 1 : 0; }
  __syncthreads();
  if (tid == 0) {
    const float D = dred[0] + dred[1] + dred[2] + dred[3];
    const float C = cred[0] + cred[1] + cred[2] + cred[3];
    const float A = ared[0] + ared[1] + ared[2] + ared[3];
    const float mlpp = (A - C * __logf(D + 1e-6f)) / (C + 1e-6f);
    row_val[row] = -mlpp / (float)L;
    row_bad[row] = bred[0] | bred[1] | bred[2] | bred[3];
  }
}

// ---------------- finalize (single block, deterministic) ----------------
__global__ __launch_bounds__(256) void final_kernel(const float* __restrict__ row_val,
                                                    const int* __restrict__ row_bad,
                                                    float* __restrict__ out) {
  const int tid  = threadIdx.x;
  const int lane = tid & 63;
  const int wave = tid >> 6;
  __shared__ int vb[B_DIM];
  if (tid < B_DIM) vb[tid] = 0;
  __syncthreads();
  float lsum = 0.f;
  for (int idx = tid; idx < B_DIM * T_DIM; idx += 256) {
    lsum += row_val[idx];
    if (row_bad[idx]) atomicOr(&vb[idx >> 10], 1);
  }
  for (int o = 32; o > 0; o >>= 1) lsum += __shfl_down(lsum, o, 64);
  __shared__ float part[4];
  if (lane == 0) part[wave] = lsum;
  __syncthreads();
  if (tid == 0) {
    const float total = part[0] + part[1] + part[2] + part[3];
    int v = 0;
    for (int b = 0; b < B_DIM; b++) v += (vb[b] ? 1 : 0);
    out[0] = total / fmaxf((float)v, 1.0f);
  }
}

extern "C" void kernel_launch(void* const* d_in, const int* in_sizes, int n_in,
                              void* d_out, int out_size, void* d_ws, size_t ws_size,
                              hipStream_t stream) {
  const float* feat = (const float*)d_in[0];
  const float* mask = (const float*)d_in[1];
  const int*   icl  = (const int*)d_in[2];
  float* out = (float*)d_out;

  char* ws = (char*)d_ws;
  __hip_bfloat16* Fb = (__hip_bfloat16*)ws;                   // 16 MiB
  float* S        = (float*)(ws + (16u << 20));               // 32 MiB
  float* row_val  = (float*)(ws + (48u << 20));               // 32 KiB
  int*   row_bad  = (int*)(ws + (48u << 20) + (32u << 10));   // 32 KiB

  convert_kernel<<<dim3(8192), dim3(256), 0, stream>>>(feat, Fb);
  gram_kernel<<<dim3(8, 8, 8), dim3(256), 0, stream>>>(Fb, S);
  row_kernel<<<dim3(8192), dim3(256), 0, stream>>>(S, mask, icl, row_val, row_bad);
  final_kernel<<<dim3(1), dim3(256), 0, stream>>>(row_val, row_bad, out);
}